// Round 1
// baseline (117.380 us; speedup 1.0000x reference)
//
#include <hip/hip_runtime.h>
#include <math.h>

// Problem constants
#define DD 256
#define HH 8
#define AA 32
#define SS 512
#define BB 2
constexpr float BCONST      = 0.9f;
constexpr float ONE_MINUS_B = 0.1f;
constexpr float EPSF        = 1e-10f;
constexpr float SCALEF      = 0.0625f;   // 1/sqrt(256), exact power of 2

typedef unsigned short u16;
typedef __attribute__((ext_vector_type(4))) u16   u16x4;
typedef __attribute__((ext_vector_type(8))) short bf16x8;  // 8 bf16 bits (4 VGPRs)
typedef __attribute__((ext_vector_type(4))) float f32x4;

// Workspace layout (float offsets)
#define OFF_QKV    0          // 1024x768 f32
#define OFF_VP     786432     // 1024x256 f32
#define OFF_EWH    1048576    // 1024x256 bf16 (131072 f-slots)
#define OFF_EWL    1179648
#define OFF_PMIN   1310720    // 32x256
#define OFF_PMAX   1318912
#define OFF_VMIN   1327104
#define OFF_VRANGE 1327616
#define OFF_P      1328128
#define OFF_AH     1328384    // ctx hi/lo: 1024x256 bf16
#define OFF_AL     1459456
#define OFF_WH     1590528    // [WQ;WKV] hi/lo: 768x256 bf16
#define OFF_WL     1688832
#define OFF_WOH    1787136    // WOUT hi/lo: 256x256 bf16
#define OFF_WOL    1819904

// Swizzled chunk buffer: row-major LD=32 floats, bank-quad ^= (row>>2)&7.
#define KB4(buf, row, col4) \
  (&(buf)[((row) << 5) | ((((col4) >> 2) ^ (((row) >> 2) & 7)) << 2)])

__device__ __forceinline__ u16 f2bf(float x) {          // RNE f32 -> bf16
  unsigned u = __float_as_uint(x);
  return (u16)((u + 0x7fffu + ((u >> 16) & 1u)) >> 16);
}
__device__ __forceinline__ float bf2f(u16 h) {
  return __uint_as_float((unsigned)h << 16);
}

// Fragment load for mfma_f32_16x16x32_bf16 from a row-major [*][256] bf16
// array: regs 0..3 = k0+4g+j, regs 4..7 = k0+16+4g+j. Both A and B operands
// use the same (g,j)->k mapping, so the contraction is layout-permutation
// invariant; only the HW-verified C/D mapping matters for addressing.
__device__ __forceinline__ bf16x8 ldfrag(const u16* p) {
  u16x4 a = *(const u16x4*)p;
  u16x4 b = *(const u16x4*)(p + 16);
  bf16x8 r;
  r[0] = (short)a[0]; r[1] = (short)a[1]; r[2] = (short)a[2]; r[3] = (short)a[3];
  r[4] = (short)b[0]; r[5] = (short)b[1]; r[6] = (short)b[2]; r[7] = (short)b[3];
  return r;
}

// ---------------------------------------------------------------------------
// fp32 -> (bf16 hi, bf16 lo) split of all GEMM inputs in one pass.
// Linear element ranges: ctx 0..262143 | WQ ..327679 | WKV ..458751 | WOUT ..524287
// ---------------------------------------------------------------------------
__global__ __launch_bounds__(256) void splitk(
    const float* __restrict__ ctx, const float* __restrict__ WQ,
    const float* __restrict__ WKV, const float* __restrict__ WOUT,
    u16* __restrict__ Ah, u16* __restrict__ Al,
    u16* __restrict__ Wh, u16* __restrict__ Wl,
    u16* __restrict__ WOh, u16* __restrict__ WOl) {
  const int e = (blockIdx.x * 256 + threadIdx.x) * 4;
  const float* src; u16 *dh, *dl;
  if (e < 262144)      { src = ctx  + e;            dh = Ah  + e;            dl = Al  + e; }
  else if (e < 327680) { src = WQ   + (e - 262144); dh = Wh  + (e - 262144); dl = Wl  + (e - 262144); }
  else if (e < 458752) { src = WKV  + (e - 327680); dh = Wh  + (e - 262144); dl = Wl  + (e - 262144); }
  else                 { src = WOUT + (e - 458752); dh = WOh + (e - 458752); dl = WOl + (e - 458752); }
  float4 v = *(const float4*)src;
  ushort4 h, l;
  h.x = f2bf(v.x); l.x = f2bf(v.x - bf2f(h.x));
  h.y = f2bf(v.y); l.y = f2bf(v.y - bf2f(h.y));
  h.z = f2bf(v.z); l.z = f2bf(v.z - bf2f(h.z));
  h.w = f2bf(v.w); l.w = f2bf(v.w - bf2f(h.w));
  *(ushort4*)dh = h;
  *(ushort4*)dl = l;
}

// ---------------------------------------------------------------------------
// Split-bf16 MFMA GEMM: C[i][j] = dot(A[i,:256], Brow(j)), fp32 accumulate.
// acc += Ahi*Bhi + Ahi*Blo + Alo*Bhi  (3 MFMAs / k-step; lo*lo ~2^-18, dropped).
// Block = 32 x (NT*32), 4 waves as 2Mx2N, wave tile 16 x (NT*16).
// No LDS staging: K=256 fragments load straight from L2-resident global.
// MM: blocks with j0>=512 (V columns) also emit per-row-tile col min/max.
// C/D layout (m89-verified): col = lane&15, row = 4*(lane>>4) + reg.
// ---------------------------------------------------------------------------
template<int NT, bool MM>
__global__ __launch_bounds__(256) void gemm_mfma(
    const u16* __restrict__ Ah, const u16* __restrict__ Al,
    const u16* __restrict__ Bh, const u16* __restrict__ Bl,
    float* __restrict__ C, int ldc,
    float* __restrict__ pminP, float* __restrict__ pmaxP) {
  __shared__ float smn[2][64], smx[2][64];
  const int t = threadIdx.x;
  const int lane = t & 63, wave = t >> 6;
  const int wm = wave >> 1, wn = wave & 1;
  const int m = lane & 15, g = lane >> 4;
  const int i0 = blockIdx.x * 32;
  const int j0 = blockIdx.y * (NT * 32);

  const size_t aoff = (size_t)(i0 + wm * 16 + m) * 256 + 4 * g;
  const u16* pAh = Ah + aoff;
  const u16* pAl = Al + aoff;
  const u16* pBh[NT]; const u16* pBl[NT];
#pragma unroll
  for (int nt = 0; nt < NT; ++nt) {
    const size_t boff = (size_t)(j0 + wn * NT * 16 + nt * 16 + m) * 256 + 4 * g;
    pBh[nt] = Bh + boff; pBl[nt] = Bl + boff;
  }

  f32x4 acc[NT] = {};
#pragma unroll
  for (int k0 = 0; k0 < 256; k0 += 32) {
    bf16x8 ah = ldfrag(pAh + k0);
    bf16x8 al = ldfrag(pAl + k0);
#pragma unroll
    for (int nt = 0; nt < NT; ++nt) {
      bf16x8 bh = ldfrag(pBh[nt] + k0);
      bf16x8 bl = ldfrag(pBl[nt] + k0);
      acc[nt] = __builtin_amdgcn_mfma_f32_16x16x32_bf16(ah, bh, acc[nt], 0, 0, 0);
      acc[nt] = __builtin_amdgcn_mfma_f32_16x16x32_bf16(ah, bl, acc[nt], 0, 0, 0);
      acc[nt] = __builtin_amdgcn_mfma_f32_16x16x32_bf16(al, bh, acc[nt], 0, 0, 0);
    }
  }

  const int crow0 = i0 + wm * 16 + 4 * g;
  const int ccol0 = j0 + wn * NT * 16 + m;
#pragma unroll
  for (int nt = 0; nt < NT; ++nt)
#pragma unroll
    for (int r = 0; r < 4; ++r)
      C[(size_t)(crow0 + r) * ldc + ccol0 + nt * 16] = acc[nt][r];

  if (MM && j0 >= 512) {
#pragma unroll
    for (int nt = 0; nt < NT; ++nt) {
      float mn = fminf(fminf(acc[nt][0], acc[nt][1]), fminf(acc[nt][2], acc[nt][3]));
      float mx = fmaxf(fmaxf(acc[nt][0], acc[nt][1]), fmaxf(acc[nt][2], acc[nt][3]));
      mn = fminf(mn, __shfl_xor(mn, 16)); mx = fmaxf(mx, __shfl_xor(mx, 16));
      mn = fminf(mn, __shfl_xor(mn, 32)); mx = fmaxf(mx, __shfl_xor(mx, 32));
      if (g == 0) {
        smn[wm][wn * NT * 16 + nt * 16 + m] = mn;
        smx[wm][wn * NT * 16 + nt * 16 + m] = mx;
      }
    }
    __syncthreads();
    if (t < NT * 32) {
      pminP[(i0 >> 5) * 256 + (j0 - 512) + t] = fminf(smn[0][t], smn[1][t]);
      pmaxP[(i0 >> 5) * 256 + (j0 - 512) + t] = fmaxf(smx[0][t], smx[1][t]);
    }
  }
}

// ---------------------------------------------------------------------------
// vp = expm1(p * log(v_norm)); also vmin / vrange per (b,d) and pw.
// 16 row-tile partials per batch (row-tile = 32 rows, matches gemm_mfma).
// ---------------------------------------------------------------------------
__global__ __launch_bounds__(256) void vpk(
    const float* __restrict__ qkv, const float* __restrict__ pminP,
    const float* __restrict__ pmaxP, const float* __restrict__ p_param,
    float* __restrict__ vp, float* __restrict__ vminw,
    float* __restrict__ vrangew, float* __restrict__ pw) {
  const int blk = blockIdx.x;           // 0..1023
  const int b = blk >> 9, s = blk & 511;
  const int d = threadIdx.x;
  float mn = pminP[(b * 16) * 256 + d];
  float mx = pmaxP[(b * 16) * 256 + d];
#pragma unroll
  for (int c = 1; c < 16; ++c) {
    mn = fminf(mn, pminP[(b * 16 + c) * 256 + d]);
    mx = fmaxf(mx, pmaxP[(b * 16 + c) * 256 + d]);
  }
  float p = 50000.0f * tanhf(0.005f * p_param[d]) + 1.0f;
  if (p == 0.0f) p = 0.0001f;
  const float range = mx - mn + EPSF;
  const float v  = qkv[((size_t)(b * 512 + s)) * 768 + 512 + d];
  const float vn = (ONE_MINUS_B * (v - mn)) / range + BCONST;
  vp[(size_t)blk * 256 + d] = expm1f(p * logf(vn));
  if (s == 0) { vminw[b * 256 + d] = mn; vrangew[b * 256 + d] = range; }
  if (blk == 0) pw[d] = p;
}

// ---------------------------------------------------------------------------
// Fused attention (unchanged math): scores + inline softmax + PV + power-mean
// epilogue. Only change vs the 107us version: epilogue stores ew as bf16
// hi/lo pair (feeds the MFMA output projection). grid = (S/32, B*H).
// ---------------------------------------------------------------------------
__global__ __launch_bounds__(256) void attn_k(
    const float* __restrict__ qkv, const float* __restrict__ vp,
    const float* __restrict__ pw, const float* __restrict__ vminw,
    const float* __restrict__ vrangew,
    u16* __restrict__ ewh, u16* __restrict__ ewl) {
  __shared__ float qs[32][36];
  __shared__ float sc[32 * 516];       // [q][k] unnormalized softmax e
  __shared__ float kb[512 * 32];       // swizzled K / VP panel (reused: part)
  __shared__ float red[32];            // per-row sum T
  const int bh  = blockIdx.y;
  const int b   = bh >> 3, h = bh & 7;
  const int q0g = blockIdx.x * 32;
  const int t   = threadIdx.x;
  const int srow = t >> 3, scol4 = (t & 7) << 2;

  // q tile (32 x 32), fold in SCALE (exact *2^-4)
  {
    const int q = t >> 3, c4 = (t & 7) << 2;
    float4 qv = *(const float4*)(qkv + ((size_t)(b * 512 + q0g + q)) * 768 + h * 32 + c4);
    qv.x *= SCALEF; qv.y *= SCALEF; qv.z *= SCALEF; qv.w *= SCALEF;
    *(float4*)&qs[q][c4] = qv;
  }
  // stage FULL K panel (512 rows)
#pragma unroll 8
  for (int u = 0; u < 16; ++u) {
    const int r = srow + 32 * u;
    float4 v = *(const float4*)(qkv + ((size_t)(b * 512 + r)) * 768 + 256 + h * 32 + scol4);
    *(float4*)KB4(kb, r, scol4) = v;
  }
  __syncthreads();

  // ---- Phase 1: scores + inline softmax. thread = 8q (qgw+4r) x 8k.
  {
    const int qgw = t >> 6;            // wave id: wave-uniform q group
    const int kg  = t & 63;            // k cols kg*4..+3 and 256+kg*4..+3
    float s8[8][8] = {};
#pragma unroll 2
    for (int kk = 0; kk < 32; kk += 4) {
      float4 qf[8], kf1[4], kf2[4];
#pragma unroll
      for (int r = 0; r < 8; ++r) qf[r] = *(const float4*)&qs[qgw + 4 * r][kk];
#pragma unroll
      for (int c = 0; c < 4; ++c) {
        kf1[c] = *(const float4*)KB4(kb, kg * 4 + c, kk);
        kf2[c] = *(const float4*)KB4(kb, 256 + kg * 4 + c, kk);
      }
#pragma unroll
      for (int r = 0; r < 8; ++r)
#pragma unroll
        for (int c = 0; c < 4; ++c) {
          s8[r][c]     += qf[r].x * kf1[c].x + qf[r].y * kf1[c].y +
                          qf[r].z * kf1[c].z + qf[r].w * kf1[c].w;
          s8[r][4 + c] += qf[r].x * kf2[c].x + qf[r].y * kf2[c].y +
                          qf[r].z * kf2[c].z + qf[r].w * kf2[c].w;
        }
    }
    // exp in registers + per-row local sums
    float rs[8];
#pragma unroll
    for (int r = 0; r < 8; ++r) {
      float s = 0.f;
#pragma unroll
      for (int c = 0; c < 8; ++c) {
        s8[r][c] = __expf(s8[r][c]);
        s += s8[r][c];
      }
      rs[r] = s;
    }
    // wave butterfly: full row sums (row qgw+4r owned entirely by wave qgw)
#pragma unroll
    for (int m = 1; m < 64; m <<= 1)
#pragma unroll
      for (int r = 0; r < 8; ++r) rs[r] += __shfl_xor(rs[r], m);
    if ((t & 63) == 0)
#pragma unroll
      for (int r = 0; r < 8; ++r) red[qgw + 4 * r] = rs[r];
    // write unnormalized e
#pragma unroll
    for (int r = 0; r < 8; ++r) {
      const int rq = qgw + 4 * r;
      *(float4*)&sc[rq * 516 + kg * 4] =
          make_float4(s8[r][0], s8[r][1], s8[r][2], s8[r][3]);
      *(float4*)&sc[rq * 516 + 256 + kg * 4] =
          make_float4(s8[r][4], s8[r][5], s8[r][6], s8[r][7]);
    }
  }
  __syncthreads();                     // sc/red done; kb K-reads done

  // ---- stage FULL VP panel into kb
#pragma unroll 8
  for (int u = 0; u < 16; ++u) {
    const int r = srow + 32 * u;
    float4 v = *(const float4*)(vp + ((size_t)(b * 512 + r)) * 256 + h * 32 + scol4);
    *(float4*)KB4(kb, r, scol4) = v;
  }
  __syncthreads();

  // ---- Phase 3: ACC[q][a] = sum_k e[q][k]*vp[k][a]; thread = 8q x 4a,
  // 8-way k-split (64 k per slice).
  const int ag  = t & 7;               // a cols ag*4..+3
  const int qg3 = (t >> 3) & 3;        // q rows qg3+4r
  const int ks  = t >> 5;              // 0..7
  float a3[8][4] = {};
#pragma unroll 2
  for (int g = 0; g < 16; ++g) {
    const int kbase = ks * 64 + g * 4;
    float4 sq[8], vf[4];
#pragma unroll
    for (int r = 0; r < 8; ++r)
      sq[r] = *(const float4*)&sc[(qg3 + 4 * r) * 516 + kbase];
#pragma unroll
    for (int c = 0; c < 4; ++c)
      vf[c] = *(const float4*)KB4(kb, kbase + c, ag * 4);
#pragma unroll
    for (int r = 0; r < 8; ++r) {
      a3[r][0] += sq[r].x * vf[0].x + sq[r].y * vf[1].x + sq[r].z * vf[2].x + sq[r].w * vf[3].x;
      a3[r][1] += sq[r].x * vf[0].y + sq[r].y * vf[1].y + sq[r].z * vf[2].y + sq[r].w * vf[3].y;
      a3[r][2] += sq[r].x * vf[0].z + sq[r].y * vf[1].z + sq[r].z * vf[2].z + sq[r].w * vf[3].z;
      a3[r][3] += sq[r].x * vf[0].w + sq[r].y * vf[1].w + sq[r].z * vf[2].w + sq[r].w * vf[3].w;
    }
  }

  // ---- fold ks pair within wave (wave w holds ks = 2w, 2w+1)
#pragma unroll
  for (int r = 0; r < 8; ++r)
#pragma unroll
    for (int c = 0; c < 4; ++c)
      a3[r][c] += __shfl_xor(a3[r][c], 32);
  __syncthreads();                     // kb reads done; reuse as part
  float* part = &kb[0];                // [w4][32*36]
  if ((t & 32) == 0) {
    const int w = t >> 6;
#pragma unroll
    for (int r = 0; r < 8; ++r)
#pragma unroll
      for (int c = 0; c < 4; ++c)
        part[w * 1152 + (qg3 + 4 * r) * 36 + ag * 4 + c] = a3[r][c];
  }
  __syncthreads();

  // ---- final 4-wave reduction + robust power-mean epilogue (4 outputs/thr)
  {
    const int q = t >> 3, a0 = (t & 7) << 2;
    const int d0 = h * 32 + a0;
    const float invT = 1.0f / red[q];
    float4 s0 = *(const float4*)&part[q * 36 + a0];
    float4 s1 = *(const float4*)&part[1152 + q * 36 + a0];
    float4 s2 = *(const float4*)&part[2304 + q * 36 + a0];
    float4 s3 = *(const float4*)&part[3456 + q * 36 + a0];
    const float4 pp = *(const float4*)(pw + d0);
    const float4 vr = *(const float4*)(vrangew + b * 256 + d0);
    const float4 vm = *(const float4*)(vminw + b * 256 + d0);
    float4 o;
    o.x = (expf(log1pf((s0.x + s1.x + s2.x + s3.x) * invT) / pp.x) - BCONST) * vr.x / ONE_MINUS_B + vm.x;
    o.y = (expf(log1pf((s0.y + s1.y + s2.y + s3.y) * invT) / pp.y) - BCONST) * vr.y / ONE_MINUS_B + vm.y;
    o.z = (expf(log1pf((s0.z + s1.z + s2.z + s3.z) * invT) / pp.z) - BCONST) * vr.z / ONE_MINUS_B + vm.z;
    o.w = (expf(log1pf((s0.w + s1.w + s2.w + s3.w) * invT) / pp.w) - BCONST) * vr.w / ONE_MINUS_B + vm.w;
    // store as bf16 hi/lo split for the MFMA output projection
    ushort4 oh, ol;
    oh.x = f2bf(o.x); ol.x = f2bf(o.x - bf2f(oh.x));
    oh.y = f2bf(o.y); ol.y = f2bf(o.y - bf2f(oh.y));
    oh.z = f2bf(o.z); ol.z = f2bf(o.z - bf2f(oh.z));
    oh.w = f2bf(o.w); ol.w = f2bf(o.w - bf2f(oh.w));
    const size_t base = ((size_t)(b * 512 + q0g + q)) * 256 + d0;
    *(ushort4*)(ewh + base) = oh;
    *(ushort4*)(ewl + base) = ol;
  }
}

// ---------------------------------------------------------------------------
extern "C" void kernel_launch(void* const* d_in, const int* in_sizes, int n_in,
                              void* d_out, int out_size, void* d_ws, size_t ws_size,
                              hipStream_t stream) {
  const float* ctx  = (const float*)d_in[0];
  const float* WQ   = (const float*)d_in[1];
  const float* WKV  = (const float*)d_in[2];
  const float* WOUT = (const float*)d_in[3];
  const float* PP   = (const float*)d_in[4];
  float* ws      = (float*)d_ws;
  float* qkv     = ws + OFF_QKV;
  float* vp      = ws + OFF_VP;
  u16*   ewh     = (u16*)(ws + OFF_EWH);
  u16*   ewl     = (u16*)(ws + OFF_EWL);
  float* pminP   = ws + OFF_PMIN;
  float* pmaxP   = ws + OFF_PMAX;
  float* vminw   = ws + OFF_VMIN;
  float* vrangew = ws + OFF_VRANGE;
  float* pw      = ws + OFF_P;
  u16*   Ah      = (u16*)(ws + OFF_AH);
  u16*   Al      = (u16*)(ws + OFF_AL);
  u16*   Wh      = (u16*)(ws + OFF_WH);
  u16*   Wl      = (u16*)(ws + OFF_WL);
  u16*   WOh     = (u16*)(ws + OFF_WOH);
  u16*   WOl     = (u16*)(ws + OFF_WOL);
  float* out     = (float*)d_out;

  // fp32 -> bf16 hi/lo split of ctx, [WQ;WKV], WOUT (524288 elems)
  splitk<<<512, 256, 0, stream>>>(ctx, WQ, WKV, WOUT, Ah, Al, Wh, Wl, WOh, WOl);
  // Fused Q|K|V projection via split-bf16 MFMA + V min/max partials:
  // 1024x768x256, 32x64 blocks
  gemm_mfma<2, true><<<dim3(32, 12), 256, 0, stream>>>(
      Ah, Al, Wh, Wl, qkv, 768, pminP, pmaxP);
  // expm1(p * log(v_norm)) + p vector + vmin/vrange (16 partials/batch)
  vpk<<<1024, 256, 0, stream>>>(qkv, pminP, pmaxP, PP, vp, vminw, vrangew, pw);
  // Fused attention + inline softmax + power-mean epilogue (emits bf16 hi/lo)
  attn_k<<<dim3(16, 16), 256, 0, stream>>>(qkv, vp, pw, vminw, vrangew, ewh, ewl);
  // Output projection via split-bf16 MFMA: 1024x256x256, 32x32 blocks
  gemm_mfma<1, false><<<dim3(32, 8), 256, 0, stream>>>(
      ewh, ewl, WOh, WOl, out, 256, nullptr, nullptr);
}

// Round 2
// 109.810 us; speedup vs baseline: 1.0689x; 1.0689x over previous
//
#include <hip/hip_runtime.h>
#include <math.h>

// Problem constants
#define DD 256
#define HH 8
#define AA 32
#define SS 512
#define BB 2
constexpr float BCONST      = 0.9f;
constexpr float ONE_MINUS_B = 0.1f;
constexpr float EPSF        = 1e-10f;
constexpr float SCALEF      = 0.0625f;   // 1/sqrt(256), exact power of 2
constexpr float FLTMAX      = 3.402823466e38f;

// Workspace layout (float offsets)
#define OFF_QKV 0          // 1024x768 f32
#define OFF_EW  786432     // 1024x256 f32

// Swizzled chunk buffer: row-major LD=32 floats, bank-quad ^= (row>>2)&7.
#define KB4(buf, row, col4) \
  (&(buf)[((row) << 5) | ((((col4) >> 2) ^ (((row) >> 2) & 7)) << 2)])

// ---------------------------------------------------------------------------
// Tiled fp32 GEMM (R9 config — proven best): C[i][j] = dot(A[i,:K], Brow(j)).
// (min/max epilogue dropped: attention blocks now compute V min/max locally.)
// ---------------------------------------------------------------------------
template<int TM, int TN, int RM, int RN>
__global__ __launch_bounds__(256) void gemm_t(
    const float* __restrict__ A, const float* __restrict__ B0,
    const float* __restrict__ B1, int nsplit,
    float* __restrict__ C, int ldc, int K, int lda) {
  constexpr int LDT = 36;
  constexpr int CG  = TN / RN;
  constexpr int NA  = TM * 32 / 1024;
  constexpr int NB  = TN * 32 / 1024;
  __shared__ float As[TM][LDT];
  __shared__ float Bs[TN][LDT];
  const int i0 = blockIdx.x * TM;
  const int j0 = blockIdx.y * TN;
  const float* Bsrc = (j0 < nsplit) ? (B0 + (size_t)j0 * K)
                                    : (B1 + (size_t)(j0 - nsplit) * K);
  const int t  = threadIdx.x;
  const int lr = t >> 3;
  const int lc = (t & 7) << 2;
  const int tx = t % CG, ty = t / CG;

  float4 pa[NA], pb[NB];
#pragma unroll
  for (int u = 0; u < NA; ++u)
    pa[u] = *(const float4*)(A + (size_t)(i0 + lr + 32 * u) * lda + lc);
#pragma unroll
  for (int u = 0; u < NB; ++u)
    pb[u] = *(const float4*)(Bsrc + (size_t)(lr + 32 * u) * K + lc);

  float acc[RM][RN] = {};
  for (int k0 = 0; k0 < K; k0 += 32) {
    __syncthreads();
#pragma unroll
    for (int u = 0; u < NA; ++u) *(float4*)&As[lr + 32 * u][lc] = pa[u];
#pragma unroll
    for (int u = 0; u < NB; ++u) *(float4*)&Bs[lr + 32 * u][lc] = pb[u];
    __syncthreads();
    if (k0 + 32 < K) {
#pragma unroll
      for (int u = 0; u < NA; ++u)
        pa[u] = *(const float4*)(A + (size_t)(i0 + lr + 32 * u) * lda + k0 + 32 + lc);
#pragma unroll
      for (int u = 0; u < NB; ++u)
        pb[u] = *(const float4*)(Bsrc + (size_t)(lr + 32 * u) * K + k0 + 32 + lc);
    }
#pragma unroll
    for (int kk = 0; kk < 32; kk += 4) {
      float4 af[RM], bf[RN];
#pragma unroll
      for (int r = 0; r < RM; ++r) af[r] = *(const float4*)&As[ty * RM + r][kk];
#pragma unroll
      for (int c = 0; c < RN; ++c) bf[c] = *(const float4*)&Bs[tx + CG * c][kk];
#pragma unroll
      for (int r = 0; r < RM; ++r)
#pragma unroll
        for (int c = 0; c < RN; ++c)
          acc[r][c] += af[r].x * bf[c].x + af[r].y * bf[c].y +
                       af[r].z * bf[c].z + af[r].w * bf[c].w;
    }
  }
#pragma unroll
  for (int r = 0; r < RM; ++r)
#pragma unroll
    for (int c = 0; c < RN; ++c)
      C[(size_t)(i0 + ty * RM + r) * ldc + j0 + tx + CG * c] = acc[r][c];
}

// ---------------------------------------------------------------------------
// Fused attention, now also absorbing the old vpk kernel:
//  - early V read -> per-column (b,d) min/max via wave butterflies + LDS
//    (block (b,h,*) owns ALL 512 rows of its 32 V columns, so min/max is
//    block-local; 16 q-tile blocks recompute it redundantly — cheap)
//  - p = 50000*tanh(0.005*pp)+1 computed by 32 threads
//  - VP staging applies expm1(p*log(vnorm)) inline (no vp global round-trip)
//  - epilogue reads p / vmin / vrange from LDS, writes ew f32
// Everything else identical to the 107.6us R9+inline-softmax structure.
// grid = (S/32, B*H).
// ---------------------------------------------------------------------------
__global__ __launch_bounds__(256) void attn_k(
    const float* __restrict__ qkv, const float* __restrict__ p_param,
    float* __restrict__ ew) {
  __shared__ float qs[32][36];
  __shared__ float sc[32 * 516];       // [q][k] unnormalized softmax e
  __shared__ float kb[512 * 32];       // swizzled K / VP panel (reused: part)
  __shared__ float red[32];            // per-row sum T
  __shared__ __align__(16) float wmn[128], wmx[128];   // per-wave minmax partials
  __shared__ __align__(16) float mnL[32], rgL[32], ivL[32], pL[32];
  const int bh  = blockIdx.y;
  const int b   = bh >> 3, h = bh & 7;
  const int q0g = blockIdx.x * 32;
  const int t   = threadIdx.x;
  const int lane = t & 63, wave = t >> 6;
  const int srow = t >> 3, scol4 = (t & 7) << 2;

  // q tile (32 x 32), fold in SCALE (exact *2^-4)
  {
    const int q = t >> 3, c4 = (t & 7) << 2;
    float4 qv = *(const float4*)(qkv + ((size_t)(b * 512 + q0g + q)) * 768 + h * 32 + c4);
    qv.x *= SCALEF; qv.y *= SCALEF; qv.z *= SCALEF; qv.w *= SCALEF;
    *(float4*)&qs[q][c4] = qv;
  }
  // stage FULL K panel (512 rows)
#pragma unroll 8
  for (int u = 0; u < 16; ++u) {
    const int r = srow + 32 * u;
    float4 v = *(const float4*)(qkv + ((size_t)(b * 512 + r)) * 768 + 256 + h * 32 + scol4);
    *(float4*)KB4(kb, r, scol4) = v;
  }
  // early V pass: per-thread min/max over its 16 rows x 4 cols (registers only)
  {
    float4 vmn4 = make_float4(FLTMAX, FLTMAX, FLTMAX, FLTMAX);
    float4 vmx4 = make_float4(-FLTMAX, -FLTMAX, -FLTMAX, -FLTMAX);
#pragma unroll 4
    for (int u = 0; u < 16; ++u) {
      const int r = srow + 32 * u;
      float4 v = *(const float4*)(qkv + ((size_t)(b * 512 + r)) * 768 + 512 + h * 32 + scol4);
      vmn4.x = fminf(vmn4.x, v.x); vmx4.x = fmaxf(vmx4.x, v.x);
      vmn4.y = fminf(vmn4.y, v.y); vmx4.y = fmaxf(vmx4.y, v.y);
      vmn4.z = fminf(vmn4.z, v.z); vmx4.z = fmaxf(vmx4.z, v.z);
      vmn4.w = fminf(vmn4.w, v.w); vmx4.w = fmaxf(vmx4.w, v.w);
    }
    // butterfly over the 8 srow-groups within the wave (lane bits 3..5)
#pragma unroll
    for (int m = 8; m <= 32; m <<= 1) {
      vmn4.x = fminf(vmn4.x, __shfl_xor(vmn4.x, m)); vmx4.x = fmaxf(vmx4.x, __shfl_xor(vmx4.x, m));
      vmn4.y = fminf(vmn4.y, __shfl_xor(vmn4.y, m)); vmx4.y = fmaxf(vmx4.y, __shfl_xor(vmx4.y, m));
      vmn4.z = fminf(vmn4.z, __shfl_xor(vmn4.z, m)); vmx4.z = fmaxf(vmx4.z, __shfl_xor(vmx4.z, m));
      vmn4.w = fminf(vmn4.w, __shfl_xor(vmn4.w, m)); vmx4.w = fmaxf(vmx4.w, __shfl_xor(vmx4.w, m));
    }
    if ((lane >> 3) == 0) {            // one writer per (wave, col-quad)
      *(float4*)&wmn[wave * 32 + scol4] = vmn4;
      *(float4*)&wmx[wave * 32 + scol4] = vmx4;
    }
  }
  // p vector for this head's 32 columns
  if (t < 32) {
    float pv = 50000.0f * tanhf(0.005f * p_param[h * 32 + t]) + 1.0f;
    if (pv == 0.0f) pv = 0.0001f;
    pL[t] = pv;
  }
  __syncthreads();

  // finish min/max reduction: column t over the 4 wave partials
  if (t < 32) {
    float mn = fminf(fminf(wmn[t], wmn[32 + t]), fminf(wmn[64 + t], wmn[96 + t]));
    float mx = fmaxf(fmaxf(wmx[t], wmx[32 + t]), fmaxf(wmx[64 + t], wmx[96 + t]));
    const float rg = mx - mn + EPSF;
    mnL[t] = mn; rgL[t] = rg; ivL[t] = ONE_MINUS_B / rg;
  }

  // ---- Phase 1: scores + inline softmax. thread = 8q (qgw+4r) x 8k.
  {
    const int qgw = t >> 6;            // wave id: wave-uniform q group
    const int kg  = t & 63;            // k cols kg*4..+3 and 256+kg*4..+3
    float s8[8][8] = {};
#pragma unroll 2
    for (int kk = 0; kk < 32; kk += 4) {
      float4 qf[8], kf1[4], kf2[4];
#pragma unroll
      for (int r = 0; r < 8; ++r) qf[r] = *(const float4*)&qs[qgw + 4 * r][kk];
#pragma unroll
      for (int c = 0; c < 4; ++c) {
        kf1[c] = *(const float4*)KB4(kb, kg * 4 + c, kk);
        kf2[c] = *(const float4*)KB4(kb, 256 + kg * 4 + c, kk);
      }
#pragma unroll
      for (int r = 0; r < 8; ++r)
#pragma unroll
        for (int c = 0; c < 4; ++c) {
          s8[r][c]     += qf[r].x * kf1[c].x + qf[r].y * kf1[c].y +
                          qf[r].z * kf1[c].z + qf[r].w * kf1[c].w;
          s8[r][4 + c] += qf[r].x * kf2[c].x + qf[r].y * kf2[c].y +
                          qf[r].z * kf2[c].z + qf[r].w * kf2[c].w;
        }
    }
    // exp in registers + per-row local sums
    float rs[8];
#pragma unroll
    for (int r = 0; r < 8; ++r) {
      float s = 0.f;
#pragma unroll
      for (int c = 0; c < 8; ++c) {
        s8[r][c] = __expf(s8[r][c]);
        s += s8[r][c];
      }
      rs[r] = s;
    }
    // wave butterfly: full row sums (row qgw+4r owned entirely by wave qgw)
#pragma unroll
    for (int m = 1; m < 64; m <<= 1)
#pragma unroll
      for (int r = 0; r < 8; ++r) rs[r] += __shfl_xor(rs[r], m);
    if ((t & 63) == 0)
#pragma unroll
      for (int r = 0; r < 8; ++r) red[qgw + 4 * r] = rs[r];
    // write unnormalized e
#pragma unroll
    for (int r = 0; r < 8; ++r) {
      const int rq = qgw + 4 * r;
      *(float4*)&sc[rq * 516 + kg * 4] =
          make_float4(s8[r][0], s8[r][1], s8[r][2], s8[r][3]);
      *(float4*)&sc[rq * 516 + 256 + kg * 4] =
          make_float4(s8[r][4], s8[r][5], s8[r][6], s8[r][7]);
    }
  }
  __syncthreads();                     // sc/red/mnL done; kb K-reads done

  // ---- stage FULL VP panel into kb, applying normalize + expm1(p*log(vn))
  {
    const float4 mnv = *(const float4*)&mnL[scol4];
    const float4 ivv = *(const float4*)&ivL[scol4];
    const float4 pv4 = *(const float4*)&pL[scol4];
#pragma unroll 4
    for (int u = 0; u < 16; ++u) {
      const int r = srow + 32 * u;
      float4 v = *(const float4*)(qkv + ((size_t)(b * 512 + r)) * 768 + 512 + h * 32 + scol4);
      v.x = expm1f(pv4.x * logf(ivv.x * (v.x - mnv.x) + BCONST));
      v.y = expm1f(pv4.y * logf(ivv.y * (v.y - mnv.y) + BCONST));
      v.z = expm1f(pv4.z * logf(ivv.z * (v.z - mnv.z) + BCONST));
      v.w = expm1f(pv4.w * logf(ivv.w * (v.w - mnv.w) + BCONST));
      *(float4*)KB4(kb, r, scol4) = v;
    }
  }
  __syncthreads();

  // ---- Phase 3: ACC[q][a] = sum_k e[q][k]*vp[k][a]; thread = 8q x 4a,
  // 8-way k-split (64 k per slice).
  const int ag  = t & 7;               // a cols ag*4..+3
  const int qg3 = (t >> 3) & 3;        // q rows qg3+4r
  const int ks  = t >> 5;              // 0..7
  float a3[8][4] = {};
#pragma unroll 2
  for (int g = 0; g < 16; ++g) {
    const int kbase = ks * 64 + g * 4;
    float4 sq[8], vf[4];
#pragma unroll
    for (int r = 0; r < 8; ++r)
      sq[r] = *(const float4*)&sc[(qg3 + 4 * r) * 516 + kbase];
#pragma unroll
    for (int c = 0; c < 4; ++c)
      vf[c] = *(const float4*)KB4(kb, kbase + c, ag * 4);
#pragma unroll
    for (int r = 0; r < 8; ++r) {
      a3[r][0] += sq[r].x * vf[0].x + sq[r].y * vf[1].x + sq[r].z * vf[2].x + sq[r].w * vf[3].x;
      a3[r][1] += sq[r].x * vf[0].y + sq[r].y * vf[1].y + sq[r].z * vf[2].y + sq[r].w * vf[3].y;
      a3[r][2] += sq[r].x * vf[0].z + sq[r].y * vf[1].z + sq[r].z * vf[2].z + sq[r].w * vf[3].z;
      a3[r][3] += sq[r].x * vf[0].w + sq[r].y * vf[1].w + sq[r].z * vf[2].w + sq[r].w * vf[3].w;
    }
  }

  // ---- fold ks pair within wave (wave w holds ks = 2w, 2w+1)
#pragma unroll
  for (int r = 0; r < 8; ++r)
#pragma unroll
    for (int c = 0; c < 4; ++c)
      a3[r][c] += __shfl_xor(a3[r][c], 32);
  __syncthreads();                     // kb reads done; reuse as part
  float* part = &kb[0];                // [w4][32*36]
  if ((t & 32) == 0) {
    const int w = t >> 6;
#pragma unroll
    for (int r = 0; r < 8; ++r)
#pragma unroll
      for (int c = 0; c < 4; ++c)
        part[w * 1152 + (qg3 + 4 * r) * 36 + ag * 4 + c] = a3[r][c];
  }
  __syncthreads();

  // ---- final 4-wave reduction + robust power-mean epilogue (4 outputs/thr)
  {
    const int q = t >> 3, a0 = (t & 7) << 2;
    const int d0 = h * 32 + a0;
    const float invT = 1.0f / red[q];
    float4 s0 = *(const float4*)&part[q * 36 + a0];
    float4 s1 = *(const float4*)&part[1152 + q * 36 + a0];
    float4 s2 = *(const float4*)&part[2304 + q * 36 + a0];
    float4 s3 = *(const float4*)&part[3456 + q * 36 + a0];
    const float4 pp = *(const float4*)&pL[a0];
    const float4 vr = *(const float4*)&rgL[a0];
    const float4 vm = *(const float4*)&mnL[a0];
    float4 o;
    o.x = (expf(log1pf((s0.x + s1.x + s2.x + s3.x) * invT) / pp.x) - BCONST) * vr.x / ONE_MINUS_B + vm.x;
    o.y = (expf(log1pf((s0.y + s1.y + s2.y + s3.y) * invT) / pp.y) - BCONST) * vr.y / ONE_MINUS_B + vm.y;
    o.z = (expf(log1pf((s0.z + s1.z + s2.z + s3.z) * invT) / pp.z) - BCONST) * vr.z / ONE_MINUS_B + vm.z;
    o.w = (expf(log1pf((s0.w + s1.w + s2.w + s3.w) * invT) / pp.w) - BCONST) * vr.w / ONE_MINUS_B + vm.w;
    *(float4*)(ew + ((size_t)(b * 512 + q0g + q)) * 256 + d0) = o;
  }
}

// ---------------------------------------------------------------------------
extern "C" void kernel_launch(void* const* d_in, const int* in_sizes, int n_in,
                              void* d_out, int out_size, void* d_ws, size_t ws_size,
                              hipStream_t stream) {
  const float* ctx  = (const float*)d_in[0];
  const float* WQ   = (const float*)d_in[1];
  const float* WKV  = (const float*)d_in[2];
  const float* WOUT = (const float*)d_in[3];
  const float* PP   = (const float*)d_in[4];
  float* ws  = (float*)d_ws;
  float* qkv = ws + OFF_QKV;
  float* ew  = ws + OFF_EW;
  float* out = (float*)d_out;

  // Fused Q|K|V projection: 1024x768x256, 32x64 tiles
  gemm_t<32, 64, 2, 4><<<dim3(32, 12), 256, 0, stream>>>(
      ctx, WQ, WKV, 256, qkv, 768, 256, 256);
  // Fused attention + vpk (min/max, p, expm1(p log vn)) + softmax + epilogue
  attn_k<<<dim3(16, 16), 256, 0, stream>>>(qkv, PP, ew);
  // Output projection: 1024x256x256, 32x32 tiles
  gemm_t<32, 32, 2, 2><<<dim3(32, 8), 256, 0, stream>>>(
      ew, WOUT, WOUT, 1 << 30, out, 256, 256, 256);
}